// Round 1
// 120.680 us; speedup vs baseline: 1.0878x; 1.0878x over previous
//
#include <hip/hip_runtime.h>
#include <math.h>

// B=1, S=4096, H=8, DH=40, D=320, fp32 in/out.  FOUR kernels:
// proj_qkv: 128x64-tile MFMA GEMM (BK=64, 5 iters) -> Qp/Kp [h][s][48]
//           (Q pre-scaled; pad carries -32 offset), Vt [h][40][4096].
// attn:     MFMA flash, R7: double-buffered LDS (1 barrier/iter), prefetch
//           distance 2, unified 3-chunk staging, hoisted zero-C, ks=4.
// combine:  sum 4 bf16 partials, normalize -> Xo [s][320] bf16.
// proj_out: 128x64-tile MFMA GEMM + bias -> out fp32.

#define NS 4096
#define ND 320
#define SCALE2 0.2281101152f      // log2(e)/sqrt(40)
#define HS48 196608               // 4096*48 per head
#define VTH 163840                // 40*4096 per head
#define XN 1310720

typedef __attribute__((ext_vector_type(8))) short bf16x8;
typedef __attribute__((ext_vector_type(16))) float f32x16;

static __device__ __forceinline__ unsigned short f2bru(float f) {
  return (unsigned short)((__builtin_bit_cast(unsigned int, f) + 0x8000u) >> 16);
}
static __device__ __forceinline__ unsigned int pk2ru(float a, float b) {
  unsigned int ua = __builtin_bit_cast(unsigned int, a) + 0x8000u;
  unsigned int ub = __builtin_bit_cast(unsigned int, b) + 0x8000u;
  return __builtin_amdgcn_perm(ub, ua, 0x07060302u);
}
static __device__ __forceinline__ unsigned int pk2t(float a, float b) {
  return __builtin_amdgcn_perm(__builtin_bit_cast(unsigned int, b),
                               __builtin_bit_cast(unsigned int, a), 0x07060302u);
}
static __device__ __forceinline__ float fexp2(float x) {
  return __builtin_amdgcn_exp2f(x);
}
static __device__ __forceinline__ bf16x8 ld8(const unsigned short* p) {
  union { uint2 u[2]; bf16x8 v; } c;
  c.u[0] = *(const uint2*)p;
  c.u[1] = *(const uint2*)(p + 4);
  return c.v;
}
static __device__ __forceinline__ uint4 ld16u(const unsigned short* p) {
  uint2 a = *(const uint2*)p, b = *(const uint2*)(p + 4);
  return make_uint4(a.x, a.y, b.x, b.y);
}
static __device__ __forceinline__ void st16(unsigned short* p, uint4 v) {
  *(uint2*)p = make_uint2(v.x, v.y);
  *(uint2*)(p + 4) = make_uint2(v.z, v.w);
}
// sigma: phys key (0..31) -> MFMA m-row so QK C/D regs land in PV A order
static __device__ __forceinline__ int sig32(int q) {
  int s = q >> 4, h2 = (q >> 3) & 1, j = q & 7;
  return (s << 4) | ((j >> 2) << 3) | (h2 << 2) | (j & 3);
}

// ---------------------------------------------------------------------------
// Kernel 1: q/k/v = x @ W^T. 128x64 tile, BK=64, 5 K-iters. grid (32, 15):
// blockIdx.y -> z = y/5 (Q/K/V), bnn = (y%5)*64. 256 thr = 4 waves, wave w
// owns rows m0=w*32 x all 64 cols (acc0 cols 0-31, acc1 cols 32-63).
// ---------------------------------------------------------------------------
__global__ __launch_bounds__(256) void proj_qkv_kernel(
    const float* __restrict__ x, const float* __restrict__ Wq,
    const float* __restrict__ Wk, const float* __restrict__ Wv,
    unsigned short* __restrict__ Qp, unsigned short* __restrict__ Kp,
    unsigned short* __restrict__ Vt) {
  const int zi = blockIdx.y;
  const int z = zi / 5;
  const int bnn = (zi - z * 5) * 64;
  const float* W = (z == 0) ? Wq : (z == 1) ? Wk : Wv;
  __shared__ __align__(16) unsigned short As[128 * 76];  // stride 38 dw: 2-way
  __shared__ __align__(16) unsigned short Bs[64 * 76];
  const int t = threadIdx.x;
  const int w = t >> 6, l = t & 63, l31 = l & 31, hi = l >> 5;
  const int bm = blockIdx.x * 128;
  const int m0 = w * 32;
  f32x16 acc0 = {0,0,0,0,0,0,0,0,0,0,0,0,0,0,0,0};
  f32x16 acc1 = {0,0,0,0,0,0,0,0,0,0,0,0,0,0,0,0};
  const unsigned short* af = As + (m0 + l31) * 76 + hi * 8;
  const unsigned short* bf0 = Bs + l31 * 76 + hi * 8;
  const unsigned short* bf1 = Bs + (32 + l31) * 76 + hi * 8;
  for (int k0 = 0; k0 < ND; k0 += 64) {
    __syncthreads();
#pragma unroll
    for (int i = 0; i < 4; i++) {            // A: 128 rows x 8 chunks(8)
      int c = t + i * 256;
      int row = c >> 3, kc = (c & 7) << 3;
      const float* g = x + (bm + row) * ND + k0 + kc;
      float4 v0 = *(const float4*)g, v1 = *(const float4*)(g + 4);
      st16(As + row * 76 + kc,
           make_uint4(pk2ru(v0.x, v0.y), pk2ru(v0.z, v0.w),
                      pk2ru(v1.x, v1.y), pk2ru(v1.z, v1.w)));
    }
#pragma unroll
    for (int i = 0; i < 2; i++) {            // B: 64 rows x 8 chunks(8)
      int c = t + i * 256;
      int row = c >> 3, kc = (c & 7) << 3;
      const float* g = W + (bnn + row) * ND + k0 + kc;
      float4 v0 = *(const float4*)g, v1 = *(const float4*)(g + 4);
      st16(Bs + row * 76 + kc,
           make_uint4(pk2ru(v0.x, v0.y), pk2ru(v0.z, v0.w),
                      pk2ru(v1.x, v1.y), pk2ru(v1.z, v1.w)));
    }
    __syncthreads();
#pragma unroll
    for (int ks = 0; ks < 4; ks++) {
      bf16x8 A = ld8(af + ks * 16);
      acc0 = __builtin_amdgcn_mfma_f32_32x32x16_bf16(A, ld8(bf0 + ks * 16), acc0, 0, 0, 0);
      acc1 = __builtin_amdgcn_mfma_f32_32x32x16_bf16(A, ld8(bf1 + ks * 16), acc1, 0, 0, 0);
    }
  }
  __syncthreads();                           // done with As/Bs; reuse as Tile
  if (z < 2) {
    // ---- Q/K epilogue: Tile [128 rows][64 cols] stride 68 over As ----
    unsigned short* Tile = As;
    unsigned short* Y = (z == 0) ? Qp : Kp;
    const float sc = (z == 0) ? SCALE2 : 1.0f;
    const unsigned int padw = (z == 0) ? 0xC200u : 0x3F80u;  // -32.0 : 1.0
#pragma unroll
    for (int r2 = 0; r2 < 16; r2++) {
      int lr = m0 + (r2 & 3) + 8 * (r2 >> 2) + 4 * hi;
      Tile[lr * 68 + l31] = f2bru(acc0[r2] * sc);
      Tile[lr * 68 + 32 + l31] = f2bru(acc1[r2] * sc);
    }
    __syncthreads();
#pragma unroll
    for (int i = 0; i < 4; i++) {            // 128 rows x 8 chunks
      int c = t + i * 256;
      int row = c >> 3, ch = c & 7;
      int j = bnn + ch * 8;
      int h = j / 40, dh = j - h * 40;
      uint4 v = ld16u(Tile + row * 68 + ch * 8);
      st16(Y + h * HS48 + (bm + row) * 48 + dh, v);
      if (dh == 0)
        st16(Y + h * HS48 + (bm + row) * 48 + 40, make_uint4(padw, 0u, 0u, 0u));
    }
  } else {
    // ---- V epilogue: transposed Tile [64 j][128 s] stride 132 over As ----
    unsigned short* Tile = As;
#pragma unroll
    for (int r2 = 0; r2 < 16; r2++) {
      int lr = m0 + (r2 & 3) + 8 * (r2 >> 2) + 4 * hi;
      Tile[l31 * 132 + lr] = f2bru(acc0[r2]);
      Tile[(32 + l31) * 132 + lr] = f2bru(acc1[r2]);
    }
    __syncthreads();
#pragma unroll
    for (int i = 0; i < 4; i++) {            // 64 j-rows x 16 s-chunks
      int c = t + i * 256;
      int row = c >> 4, ch = c & 15;
      int j = bnn + row;
      int h = j / 40, dd = j - h * 40;
      uint4 v = ld16u(Tile + row * 132 + ch * 8);
      st16(Vt + h * VTH + dd * NS + bm + ch * 8, v);
    }
  }
}

// ---------------------------------------------------------------------------
// Kernel 2: MFMA flash attention. grid 1024 x 256. h=b&7 XCD swizzle,
// ks=4 key-splits of 1024 keys, 16 iters of 64-key tiles.
// R7: double-buffered LDS (buffer stride 8192 shorts = 16 KB):
//   per buffer: K [64 sigma-rows][68] at +0, V [48 dh][68] at +4352.
// One __syncthreads per iter; reg prefetch runs 2 tiles ahead (loads for
// tile t+2 issue under compute of tile t; stores of t+1 overlap compute).
// Unified staging: 704 16B-chunks (K 384 + V 320), 3 per thread (t<192 third).
// Last-iter prefetch overruns land in adjacent ws regions (harmless).
// ---------------------------------------------------------------------------
__global__ __launch_bounds__(256, 4) void attn_kernel(
    const unsigned short* __restrict__ Qp, const unsigned short* __restrict__ Kp,
    const unsigned short* __restrict__ Vt, unsigned short* __restrict__ Op,
    float* __restrict__ Lp) {
  const int b = blockIdx.x;
  const int h = b & 7, ks = (b >> 3) & 3, qt = b >> 5;
  const int t = threadIdx.x;
  const int w = t >> 6, l = t & 63, l31 = l & 31, hi = l >> 5;
  __shared__ __align__(16) unsigned short Lds[16384];   // 2 x 16 KB buffers
  // ones row (dh=40) + zero rows 41-47 in BOTH buffers (row 40 feeds l-sum)
  for (int i = t; i < 544; i += 256) {
    int bsel = (i >= 272) ? 1 : 0;
    int ui = i - bsel * 272;
    ((unsigned int*)(Lds + bsel * 8192 + 4352 + 40 * 68))[ui] =
        (ui < 34) ? 0x3F803F80u : 0u;
  }

  const int kbase = ks * 1024;
  const int qbase = qt * 128 + w * 32;
  const unsigned short* qp = Qp + h * HS48 + (qbase + l31) * 48 + hi * 8;
  bf16x8 qf0 = *(const bf16x8*)qp;
  bf16x8 qf1 = *(const bf16x8*)(qp + 16);
  bf16x8 qf2 = *(const bf16x8*)(qp + 32);   // includes {-32,0..} pad

  const f32x16 Z = {0,0,0,0,0,0,0,0,0,0,0,0,0,0,0,0};  // hoisted zero-C
  f32x16 oa0 = Z, oa1 = Z;

  // unified staging map: chunk ids 0..383 = K (kr=id/6, kc=id%6),
  // ids 384..703 = V (vr=(id-384)>>3 in 0..39, vc=(id-384)&7).
  // thread t owns ids {t, t+256, t+512(if t<192)}.
  const int id1 = t + 256;
  const bool has2 = (t < 192);
  const int kr0 = t / 6, kc0 = t - kr0 * 6;
  const unsigned short* g0 = Kp + h * HS48 + (kbase + kr0) * 48 + kc0 * 8;
  const int w0 = ((kr0 & 32) | sig32(kr0 & 31)) * 68 + kc0 * 8;
  const unsigned short* g1;
  int w1, inc1;
  if (id1 < 384) {
    int kr = id1 / 6, kc = id1 - kr * 6;
    g1 = Kp + h * HS48 + (kbase + kr) * 48 + kc * 8;
    w1 = ((kr & 32) | sig32(kr & 31)) * 68 + kc * 8;
    inc1 = 64 * 48;
  } else {
    int vid = id1 - 384, vr = vid >> 3, vc = vid & 7;
    g1 = Vt + h * VTH + vr * NS + kbase + vc * 8;
    w1 = 4352 + vr * 68 + vc * 8;
    inc1 = 64;
  }
  const int vid2 = t + 128;                   // id2 - 384, valid for t<192
  const int vr2 = vid2 >> 3, vc2 = vid2 & 7;  // rows 16..39
  const unsigned short* g2 = Vt + h * VTH + vr2 * NS + kbase + vc2 * 8;
  const int w2 = 4352 + vr2 * 68 + vc2 * 8;

  const int rk  = l31 * 68 + hi * 8;                        // kf0 (+2176 = kf1)
  const int rv0 = 4352 + l31 * 68 + hi * 8;
  const int rv1 = 4352 + (32 + (l31 & 15)) * 68 + hi * 8;

  // prologue: tile 0 -> buf0, tile 1 -> regs
  uint4 r0 = *(const uint4*)g0; g0 += 3072;
  uint4 r1 = *(const uint4*)g1; g1 += inc1;
  uint4 r2{};
  if (has2) { r2 = *(const uint4*)g2; g2 += 64; }
  st16(Lds + w0, r0);
  st16(Lds + w1, r1);
  if (has2) st16(Lds + w2, r2);
  r0 = *(const uint4*)g0; g0 += 3072;
  r1 = *(const uint4*)g1; g1 += inc1;
  if (has2) { r2 = *(const uint4*)g2; g2 += 64; }
  __syncthreads();

  for (int it = 0; it < 16; ++it) {
    const int bo = (it & 1) << 13;
    const int bn = bo ^ 8192;
    // stage tile it+1 into the other buffer (its readers drained at the
    // barrier ending iter it-1); then issue loads for tile it+2.
    st16(Lds + bn + w0, r0);
    st16(Lds + bn + w1, r1);
    if (has2) st16(Lds + bn + w2, r2);
    r0 = *(const uint4*)g0; g0 += 3072;
    r1 = *(const uint4*)g1; g1 += inc1;
    if (has2) { r2 = *(const uint4*)g2; g2 += 64; }

    const unsigned short* kf0 = Lds + bo + rk;
    const unsigned short* kf1 = kf0 + 2176;
    const unsigned short* vf0 = Lds + bo + rv0;
    const unsigned short* vf1 = Lds + bo + rv1;

    {  // m-tile 0: phys keys 0..31 (sigma rows)
      f32x16 s0 = __builtin_amdgcn_mfma_f32_32x32x16_bf16(ld8(kf0), qf0, Z, 0, 0, 0);
      s0 = __builtin_amdgcn_mfma_f32_32x32x16_bf16(ld8(kf0 + 16), qf1, s0, 0, 0, 0);
      s0 = __builtin_amdgcn_mfma_f32_32x32x16_bf16(ld8(kf0 + 32), qf2, s0, 0, 0, 0);
      unsigned int pw[8];
#pragma unroll
      for (int i = 0; i < 8; i++)
        pw[i] = pk2t(fexp2(s0[2 * i]), fexp2(s0[2 * i + 1]));
      bf16x8 pf0 = __builtin_bit_cast(bf16x8, make_uint4(pw[0], pw[1], pw[2], pw[3]));
      bf16x8 pf1 = __builtin_bit_cast(bf16x8, make_uint4(pw[4], pw[5], pw[6], pw[7]));
      oa0 = __builtin_amdgcn_mfma_f32_32x32x16_bf16(pf0, ld8(vf0), oa0, 0, 0, 0);
      oa1 = __builtin_amdgcn_mfma_f32_32x32x16_bf16(pf0, ld8(vf1), oa1, 0, 0, 0);
      oa0 = __builtin_amdgcn_mfma_f32_32x32x16_bf16(pf1, ld8(vf0 + 16), oa0, 0, 0, 0);
      oa1 = __builtin_amdgcn_mfma_f32_32x32x16_bf16(pf1, ld8(vf1 + 16), oa1, 0, 0, 0);
    }
    {  // m-tile 1: phys keys 32..63
      f32x16 s1 = __builtin_amdgcn_mfma_f32_32x32x16_bf16(ld8(kf1), qf0, Z, 0, 0, 0);
      s1 = __builtin_amdgcn_mfma_f32_32x32x16_bf16(ld8(kf1 + 16), qf1, s1, 0, 0, 0);
      s1 = __builtin_amdgcn_mfma_f32_32x32x16_bf16(ld8(kf1 + 32), qf2, s1, 0, 0, 0);
      unsigned int pw[8];
#pragma unroll
      for (int i = 0; i < 8; i++)
        pw[i] = pk2t(fexp2(s1[2 * i]), fexp2(s1[2 * i + 1]));
      bf16x8 pf2 = __builtin_bit_cast(bf16x8, make_uint4(pw[0], pw[1], pw[2], pw[3]));
      bf16x8 pf3 = __builtin_bit_cast(bf16x8, make_uint4(pw[4], pw[5], pw[6], pw[7]));
      oa0 = __builtin_amdgcn_mfma_f32_32x32x16_bf16(pf2, ld8(vf0 + 32), oa0, 0, 0, 0);
      oa1 = __builtin_amdgcn_mfma_f32_32x32x16_bf16(pf2, ld8(vf1 + 32), oa1, 0, 0, 0);
      oa0 = __builtin_amdgcn_mfma_f32_32x32x16_bf16(pf3, ld8(vf0 + 48), oa0, 0, 0, 0);
      oa1 = __builtin_amdgcn_mfma_f32_32x32x16_bf16(pf3, ld8(vf1 + 48), oa1, 0, 0, 0);
    }
    __syncthreads();
  }

  unsigned short* opb = Op + ks * XN + h * 163840;
  float* lpb = Lp + ks * 32768 + h * NS;
#pragma unroll
  for (int r2i = 0; r2i < 16; r2i++) {
    int qr = qbase + (r2i & 3) + 8 * (r2i >> 2) + 4 * hi;
    opb[qr * 40 + l31] = f2bru(oa0[r2i]);
    if (l31 < 8) opb[qr * 40 + 32 + l31] = f2bru(oa1[r2i]);
    if (l31 == 8) lpb[qr] = oa1[r2i];   // l = Sum(p) via ones-row at dh=40
  }
}

// ---------------------------------------------------------------------------
// Kernel 3: sum 4 bf16 partials, normalize -> Xo [s][320] bf16.
// grid 2560 x 256, 2 elems/thread.
// ---------------------------------------------------------------------------
__global__ __launch_bounds__(256) void combine_kernel(
    const unsigned short* __restrict__ Op, const float* __restrict__ Lp,
    unsigned short* __restrict__ Xo) {
  int e = (blockIdx.x * 256 + threadIdx.x) * 2;    // over [h][s][40]
  int h = e / 163840;
  int r = e - h * 163840;
  int s = r / 40;
  int dh = r - s * 40;
  float a0 = 0.f, a1 = 0.f, lsum = 0.f;
#pragma unroll
  for (int k = 0; k < 4; k++) {
    unsigned int u = *(const unsigned int*)(Op + k * XN + e);
    a0 += __builtin_bit_cast(float, u << 16);
    a1 += __builtin_bit_cast(float, u & 0xFFFF0000u);
    lsum += Lp[k * 32768 + h * NS + s];
  }
  float inv = 1.0f / lsum;
  *(unsigned int*)(Xo + s * ND + h * 40 + dh) = pk2ru(a0 * inv, a1 * inv);
}

// ---------------------------------------------------------------------------
// Kernel 4: out = Xo @ Wo^T + bo. 128x64 tile, BK=64, 5 iters. grid (32, 5).
// ---------------------------------------------------------------------------
__global__ __launch_bounds__(256) void proj_out_kernel(
    const unsigned short* __restrict__ Xo, const float* __restrict__ Wo,
    const float* __restrict__ bo, float* __restrict__ out) {
  __shared__ __align__(16) unsigned short As[128 * 76];
  __shared__ __align__(16) unsigned short Bs[64 * 76];
  const int t = threadIdx.x;
  const int w = t >> 6, l = t & 63, l31 = l & 31, hi = l >> 5;
  const int bm = blockIdx.x * 128;
  const int bnn = blockIdx.y * 64;
  const int m0 = w * 32;
  f32x16 acc0 = {0,0,0,0,0,0,0,0,0,0,0,0,0,0,0,0};
  f32x16 acc1 = {0,0,0,0,0,0,0,0,0,0,0,0,0,0,0,0};
  const unsigned short* af = As + (m0 + l31) * 76 + hi * 8;
  const unsigned short* bf0 = Bs + l31 * 76 + hi * 8;
  const unsigned short* bf1 = Bs + (32 + l31) * 76 + hi * 8;
  for (int k0 = 0; k0 < ND; k0 += 64) {
    __syncthreads();
#pragma unroll
    for (int i = 0; i < 4; i++) {            // A: 128 rows x 8 chunks, bf16 src
      int c = t + i * 256;
      int row = c >> 3, kc = (c & 7) << 3;
      uint4 v = *(const uint4*)(Xo + (bm + row) * ND + k0 + kc);
      st16(As + row * 76 + kc, v);
    }
#pragma unroll
    for (int i = 0; i < 2; i++) {            // B: 64 rows x 8 chunks, fp32 src
      int c = t + i * 256;
      int row = c >> 3, kc = (c & 7) << 3;
      const float* g = Wo + (bnn + row) * ND + k0 + kc;
      float4 v0 = *(const float4*)g, v1 = *(const float4*)(g + 4);
      st16(Bs + row * 76 + kc,
           make_uint4(pk2ru(v0.x, v0.y), pk2ru(v0.z, v0.w),
                      pk2ru(v1.x, v1.y), pk2ru(v1.z, v1.w)));
    }
    __syncthreads();
#pragma unroll
    for (int ks = 0; ks < 4; ks++) {
      bf16x8 A = ld8(af + ks * 16);
      acc0 = __builtin_amdgcn_mfma_f32_32x32x16_bf16(A, ld8(bf0 + ks * 16), acc0, 0, 0, 0);
      acc1 = __builtin_amdgcn_mfma_f32_32x32x16_bf16(A, ld8(bf1 + ks * 16), acc1, 0, 0, 0);
    }
  }
  const int j0 = bnn + l31, j1 = bnn + 32 + l31;
  const float bj0 = bo[j0], bj1 = bo[j1];
#pragma unroll
  for (int r2 = 0; r2 < 16; r2++) {
    int row = bm + m0 + (r2 & 3) + 8 * (r2 >> 2) + 4 * hi;
    out[row * ND + j0] = acc0[r2] + bj0;
    out[row * ND + j1] = acc1[r2] + bj1;
  }
}

extern "C" void kernel_launch(void* const* d_in, const int* in_sizes, int n_in,
                              void* d_out, int out_size, void* d_ws, size_t ws_size,
                              hipStream_t stream) {
  (void)in_sizes; (void)n_in; (void)out_size; (void)ws_size;
  const float* x  = (const float*)d_in[0];
  const float* Wq = (const float*)d_in[1];
  const float* Wk = (const float*)d_in[2];
  const float* Wv = (const float*)d_in[3];
  const float* Wo = (const float*)d_in[4];
  const float* bo = (const float*)d_in[5];
  float* out = (float*)d_out;

  unsigned short* Qp = (unsigned short*)d_ws;   // 8*HS48
  unsigned short* Kp = Qp + 8 * HS48;           // 8*HS48
  unsigned short* Vt = Kp + 8 * HS48;           // 8*VTH
  unsigned short* Xo = Vt + 8 * VTH;            // XN
  unsigned short* Op = Xo + XN;                 // 4*XN bf16 partials
  float* Lp = (float*)(Op + 4 * XN);            // 4*32768 fp32
  // ws use ~23 MB

  proj_qkv_kernel<<<dim3(32, 15), 256, 0, stream>>>(x, Wq, Wk, Wv, Qp, Kp, Vt);
  attn_kernel<<<dim3(1024), 256, 0, stream>>>(Qp, Kp, Vt, Op, Lp);
  combine_kernel<<<dim3(2560), 256, 0, stream>>>(Op, Lp, Xo);
  proj_out_kernel<<<dim3(32, 5), 256, 0, stream>>>(Xo, Wo, bo, out);
}